// Round 3
// baseline (674.292 us; speedup 1.0000x reference)
//
#include <hip/hip_runtime.h>

#define EPS_F 1e-12f
constexpr int C = 64;

// Each wave (64 lanes) processes 4 consecutive rows per iteration.
// Lane i loads float4 at flat offset i within the 4-row block (1 KiB
// contiguous per wave -> perfectly coalesced, 16 B/lane).
// 16-lane subgroup (lane>>4 == grp) owns row row0+grp; subgroup lane
// sub = lane&15 owns columns 4*sub .. 4*sub+3.
__global__ __launch_bounds__(256) void cce_main(const float* __restrict__ x,
                                                const int* __restrict__ y,
                                                const float* __restrict__ obs,
                                                double* __restrict__ ws_sum,
                                                int N) {
    const int tid  = threadIdx.x;
    const int lane = tid & 63;
    const int sub  = lane & 15;   // position within 16-lane row group
    const int grp  = lane >> 4;   // which of the 4 rows in this chunk
    const int waveInBlock   = tid >> 6;
    const int wavesPerBlock = blockDim.x >> 6;

    const long long globalWave = (long long)blockIdx.x * wavesPerBlock + waveInBlock;
    const long long numWaves   = (long long)gridDim.x * wavesPerBlock;
    const long long numChunks  = ((long long)N + 3) >> 2;

    float acc = 0.f;

    for (long long chunk = globalWave; chunk < numChunks; chunk += numWaves) {
        const long long row0 = chunk << 2;
        const long long row  = row0 + grp;
        const bool valid = (row < (long long)N);

        float4 v = make_float4(0.f, 0.f, 0.f, 0.f);
        if (valid) {
            const float4* xv = reinterpret_cast<const float4*>(x + row0 * C);
            v = xv[lane];
        }

        // --- row max over 16-lane subgroup ---
        float m = fmaxf(fmaxf(v.x, v.y), fmaxf(v.z, v.w));
        #pragma unroll
        for (int off = 1; off < 16; off <<= 1) m = fmaxf(m, __shfl_xor(m, off));

        // --- exp and row sum ---
        const float e0 = __expf(v.x - m);
        const float e1 = __expf(v.y - m);
        const float e2 = __expf(v.z - m);
        const float e3 = __expf(v.w - m);
        float s = (e0 + e1) + (e2 + e3);
        #pragma unroll
        for (int off = 1; off < 16; off <<= 1) s += __shfl_xor(s, off);

        const float invZ = 1.0f / s;
        // clipped probabilities (reference clips p elementwise before cumsum)
        const float p0 = fmaxf(e0 * invZ, EPS_F);
        const float p1 = fmaxf(e1 * invZ, EPS_F);
        const float p2 = fmaxf(e2 * invZ, EPS_F);
        const float p3 = fmaxf(e3 * invZ, EPS_F);

        const int   yy = valid ? y[row]   : 0;
        const float ob = valid ? obs[row] : 1.f;

        const int col0 = sub << 2;

        // partial p[y]
        float py = 0.f;
        if (yy >= col0 && yy < col0 + 4) {
            const int r = yy - col0;
            py = (r == 0) ? p0 : (r == 1) ? p1 : (r == 2) ? p2 : p3;
        }
        // partial suffix sum over cols >= yy+1
        const int t = yy + 1;
        float suf = 0.f;
        if (col0 + 0 >= t) suf += p0;
        if (col0 + 1 >= t) suf += p1;
        if (col0 + 2 >= t) suf += p2;
        if (col0 + 3 >= t) suf += p3;

        #pragma unroll
        for (int off = 1; off < 16; off <<= 1) {
            py  += __shfl_xor(py,  off);
            suf += __shfl_xor(suf, off);
        }

        // observed (or y==C-1 censored, same formula): log(p_y)
        // censored: log(clip(suffix[y+1], EPS))
        const float term = (ob > 0.5f || yy == C - 1) ? __logf(py)
                                                      : __logf(fmaxf(suf, EPS_F));
        if (sub == 0 && valid) acc += term;
    }

    // --- block reduction: full-wave shfl, then LDS across waves ---
    #pragma unroll
    for (int off = 1; off < 64; off <<= 1) acc += __shfl_xor(acc, off);

    __shared__ float wsum[8];
    if (lane == 0) wsum[waveInBlock] = acc;
    __syncthreads();
    if (tid == 0) {
        float b = 0.f;
        for (int w = 0; w < wavesPerBlock; ++w) b += wsum[w];
        atomicAdd(ws_sum, (double)b);
    }
}

__global__ void cce_finalize(const double* __restrict__ ws_sum,
                             float* __restrict__ out, int N) {
    if (threadIdx.x == 0 && blockIdx.x == 0) {
        out[0] = (float)(-(*ws_sum) / (double)N);
    }
}

extern "C" void kernel_launch(void* const* d_in, const int* in_sizes, int n_in,
                              void* d_out, int out_size, void* d_ws, size_t ws_size,
                              hipStream_t stream) {
    const float* x   = (const float*)d_in[0];
    const int*   y   = (const int*)d_in[1];
    const float* obs = (const float*)d_in[2];
    int N = in_sizes[1];
    if (N <= 0) N = in_sizes[0] / C;

    double* ws_sum = (double*)d_ws;
    hipMemsetAsync(ws_sum, 0, sizeof(double), stream);

    const int block = 256;
    const long long chunks = ((long long)N + 3) >> 2;          // wave-tasks
    long long blocksNeeded = (chunks + 3) / 4;                  // 4 waves/block
    int grid = (int)((blocksNeeded < 2048) ? blocksNeeded : 2048);
    if (grid < 1) grid = 1;

    cce_main<<<grid, block, 0, stream>>>(x, y, obs, ws_sum, N);
    cce_finalize<<<1, 64, 0, stream>>>(ws_sum, (float*)d_out, N);
}

// Round 4
// 662.813 us; speedup vs baseline: 1.0173x; 1.0173x over previous
//
#include <hip/hip_runtime.h>

#define EPS_F 1e-12f
constexpr int C = 64;
typedef float f32x4 __attribute__((ext_vector_type(4)));

// One 16-lane subgroup owns one row; sub = lane&15 owns columns 4*sub..4*sub+3.
// Numerics are bit-identical per path to the round-3 kernel (absmax was 0.0):
// same max/sum/select arithmetic, same reduction order; the only change is that
// the branch select happens BEFORE the final reduce (condition is group-uniform).
__device__ __forceinline__ float process_row(f32x4 v, int yy, float ob, int sub) {
    float m = fmaxf(fmaxf(v.x, v.y), fmaxf(v.z, v.w));
    #pragma unroll
    for (int off = 1; off < 16; off <<= 1) m = fmaxf(m, __shfl_xor(m, off));

    const float e0 = __expf(v.x - m);
    const float e1 = __expf(v.y - m);
    const float e2 = __expf(v.z - m);
    const float e3 = __expf(v.w - m);
    float s = (e0 + e1) + (e2 + e3);
    #pragma unroll
    for (int off = 1; off < 16; off <<= 1) s += __shfl_xor(s, off);

    const float invZ = 1.0f / s;
    const float p0 = fmaxf(e0 * invZ, EPS_F);
    const float p1 = fmaxf(e1 * invZ, EPS_F);
    const float p2 = fmaxf(e2 * invZ, EPS_F);
    const float p3 = fmaxf(e3 * invZ, EPS_F);

    const int col0 = sub << 2;
    const bool use_py = (ob > 0.5f) || (yy == C - 1);

    float part = 0.f;
    if (use_py) {
        // partial p[y]: nonzero in exactly one lane of the group
        if (yy >= col0 && yy < col0 + 4) {
            const int r = yy - col0;
            part = (r == 0) ? p0 : (r == 1) ? p1 : (r == 2) ? p2 : p3;
        }
    } else {
        // partial suffix sum over cols >= yy+1
        const int t = yy + 1;
        if (col0 + 0 >= t) part += p0;
        if (col0 + 1 >= t) part += p1;
        if (col0 + 2 >= t) part += p2;
        if (col0 + 3 >= t) part += p3;
    }
    #pragma unroll
    for (int off = 1; off < 16; off <<= 1) part += __shfl_xor(part, off);

    // observed: part = p_y >= EPS already (clipped), fmax is a no-op there.
    return __logf(fmaxf(part, EPS_F));
}

// Each wave processes 8 consecutive rows per iteration via two independent
// float4 loads (2 KiB contiguous per wave -> coalesced, 2 outstanding loads)
// and two independent reduction pipelines (ILP across the shfl chains).
__global__ __launch_bounds__(256) void cce_main(const float* __restrict__ x,
                                                const int* __restrict__ y,
                                                const float* __restrict__ obs,
                                                double* __restrict__ ws_sum,
                                                int N) {
    const int tid  = threadIdx.x;
    const int lane = tid & 63;
    const int sub  = lane & 15;
    const int grp  = lane >> 4;
    const int waveInBlock   = tid >> 6;
    const int wavesPerBlock = blockDim.x >> 6;

    const long long NN         = N;
    const long long globalWave = (long long)blockIdx.x * wavesPerBlock + waveInBlock;
    const long long numWaves   = (long long)gridDim.x * wavesPerBlock;
    const long long numChunks  = (NN + 7) >> 3;

    float acc = 0.f;

    for (long long chunk = globalWave; chunk < numChunks; chunk += numWaves) {
        const long long row0 = chunk << 3;
        const long long rowA = row0 + grp;        // rows row0 .. row0+3
        const long long rowB = row0 + 4 + grp;    // rows row0+4 .. row0+7
        const bool vA = rowA < NN;
        const bool vB = rowB < NN;

        const f32x4* xv = reinterpret_cast<const f32x4*>(x + row0 * C);
        f32x4 a = {0.f, 0.f, 0.f, 0.f};
        f32x4 b = {0.f, 0.f, 0.f, 0.f};
        if (vA) a = __builtin_nontemporal_load(xv + lane);        // streamed once
        if (vB) b = __builtin_nontemporal_load(xv + 64 + lane);

        const int   yA = vA ? y[rowA]   : 0;
        const float oA = vA ? obs[rowA] : 1.f;
        const int   yB = vB ? y[rowB]   : 0;
        const float oB = vB ? obs[rowB] : 1.f;

        const float tA = process_row(a, yA, oA, sub);
        const float tB = process_row(b, yB, oB, sub);

        if (sub == 0) {
            if (vA) acc += tA;
            if (vB) acc += tB;
        }
    }

    // --- block reduction: full-wave shfl, then LDS across waves ---
    #pragma unroll
    for (int off = 1; off < 64; off <<= 1) acc += __shfl_xor(acc, off);

    __shared__ float wsum[8];
    if (lane == 0) wsum[waveInBlock] = acc;
    __syncthreads();
    if (tid == 0) {
        float bsum = 0.f;
        for (int w = 0; w < wavesPerBlock; ++w) bsum += wsum[w];
        atomicAdd(ws_sum, (double)bsum);
    }
}

__global__ void cce_finalize(const double* __restrict__ ws_sum,
                             float* __restrict__ out, int N) {
    if (threadIdx.x == 0 && blockIdx.x == 0) {
        out[0] = (float)(-(*ws_sum) / (double)N);
    }
}

extern "C" void kernel_launch(void* const* d_in, const int* in_sizes, int n_in,
                              void* d_out, int out_size, void* d_ws, size_t ws_size,
                              hipStream_t stream) {
    const float* x   = (const float*)d_in[0];
    const int*   y   = (const int*)d_in[1];
    const float* obs = (const float*)d_in[2];
    int N = in_sizes[1];
    if (N <= 0) N = in_sizes[0] / C;

    double* ws_sum = (double*)d_ws;
    hipMemsetAsync(ws_sum, 0, sizeof(double), stream);

    const int block = 256;
    const long long chunks = ((long long)N + 7) >> 3;           // 8-row wave-tasks
    long long blocksNeeded = (chunks + 3) / 4;                  // 4 waves/block
    int grid = (int)((blocksNeeded < 2048) ? blocksNeeded : 2048);
    if (grid < 1) grid = 1;

    cce_main<<<grid, block, 0, stream>>>(x, y, obs, ws_sum, N);
    cce_finalize<<<1, 64, 0, stream>>>(ws_sum, (float*)d_out, N);
}

// Round 5
// 648.501 us; speedup vs baseline: 1.0398x; 1.0221x over previous
//
#include <hip/hip_runtime.h>

#define EPS_F 1e-12f
constexpr int C = 64;
typedef float f32x4 __attribute__((ext_vector_type(4)));

// --- DPP 16-lane-group allreduce (no LDS pipe, pure VALU) ---------------
// quad_perm [1,0,3,2] = 0xB1 (xor 1), quad_perm [2,3,0,1] = 0x4E (xor 2),
// row_ror:4 = 0x124, row_ror:8 = 0x128 (rotation within the 16-lane row).
// For lane sub==0 (the consumed lane) this combine tree is bit-identical
// to the xor-butterfly used in the previous (absmax==0.0) kernel.
template <int CTRL>
__device__ __forceinline__ float dpp_movf(float v) {
    return __int_as_float(__builtin_amdgcn_update_dpp(
        0, __float_as_int(v), CTRL, 0xF, 0xF, false));
}
__device__ __forceinline__ float grp_max16(float v) {
    v = fmaxf(v, dpp_movf<0xB1>(v));
    v = fmaxf(v, dpp_movf<0x4E>(v));
    v = fmaxf(v, dpp_movf<0x124>(v));
    v = fmaxf(v, dpp_movf<0x128>(v));
    return v;
}
__device__ __forceinline__ float grp_sum16(float v) {
    v += dpp_movf<0xB1>(v);
    v += dpp_movf<0x4E>(v);
    v += dpp_movf<0x124>(v);
    v += dpp_movf<0x128>(v);
    return v;
}

// One 16-lane subgroup owns one row; sub = lane&15 owns cols 4*sub..4*sub+3.
__device__ __forceinline__ float process_row(f32x4 v, int yy, float ob, int sub) {
    float m = grp_max16(fmaxf(fmaxf(v.x, v.y), fmaxf(v.z, v.w)));

    const float e0 = __expf(v.x - m);
    const float e1 = __expf(v.y - m);
    const float e2 = __expf(v.z - m);
    const float e3 = __expf(v.w - m);
    const float s  = grp_sum16((e0 + e1) + (e2 + e3));

    const float invZ = 1.0f / s;
    const float p0 = fmaxf(e0 * invZ, EPS_F);
    const float p1 = fmaxf(e1 * invZ, EPS_F);
    const float p2 = fmaxf(e2 * invZ, EPS_F);
    const float p3 = fmaxf(e3 * invZ, EPS_F);

    const int col0 = sub << 2;
    const bool use_py = (ob > 0.5f) || (yy == C - 1);

    float part = 0.f;
    if (use_py) {
        if (yy >= col0 && yy < col0 + 4) {
            const int r = yy - col0;
            part = (r == 0) ? p0 : (r == 1) ? p1 : (r == 2) ? p2 : p3;
        }
    } else {
        const int t = yy + 1;
        if (col0 + 0 >= t) part += p0;
        if (col0 + 1 >= t) part += p1;
        if (col0 + 2 >= t) part += p2;
        if (col0 + 3 >= t) part += p3;
    }
    part = grp_sum16(part);
    return __logf(fmaxf(part, EPS_F));
}

// Each wave processes 16 consecutive rows per iteration: 4 independent
// float4 loads (4 KiB contiguous per wave, coalesced, 4 loads in flight)
// feeding 4 independent DPP-reduction pipelines (deep ILP, short chains).
__global__ __launch_bounds__(256) void cce_main(const float* __restrict__ x,
                                                const int* __restrict__ y,
                                                const float* __restrict__ obs,
                                                double* __restrict__ ws_sum,
                                                int N) {
    const int tid  = threadIdx.x;
    const int lane = tid & 63;
    const int sub  = lane & 15;
    const int grp  = lane >> 4;
    const int waveInBlock   = tid >> 6;
    const int wavesPerBlock = blockDim.x >> 6;

    const long long NN         = N;
    const long long globalWave = (long long)blockIdx.x * wavesPerBlock + waveInBlock;
    const long long numWaves   = (long long)gridDim.x * wavesPerBlock;
    const long long numChunks  = (NN + 15) >> 4;

    float acc = 0.f;

    for (long long chunk = globalWave; chunk < numChunks; chunk += numWaves) {
        const long long row0 = chunk << 4;
        const f32x4* xv = reinterpret_cast<const f32x4*>(x + row0 * C);

        if (row0 + 16 <= NN) {  // full chunk: branch-free hot path
            f32x4 a = __builtin_nontemporal_load(xv + lane);
            f32x4 b = __builtin_nontemporal_load(xv + 64 + lane);
            f32x4 c = __builtin_nontemporal_load(xv + 128 + lane);
            f32x4 d = __builtin_nontemporal_load(xv + 192 + lane);

            const int   yA = y[row0 + grp],        yB = y[row0 + 4 + grp];
            const int   yC = y[row0 + 8 + grp],    yD = y[row0 + 12 + grp];
            const float oA = obs[row0 + grp],      oB = obs[row0 + 4 + grp];
            const float oC = obs[row0 + 8 + grp],  oD = obs[row0 + 12 + grp];

            const float t = process_row(a, yA, oA, sub) + process_row(b, yB, oB, sub)
                          + process_row(c, yC, oC, sub) + process_row(d, yD, oD, sub);
            if (sub == 0) acc += t;
        } else {               // tail chunk (never hit for N % 16 == 0)
            #pragma unroll
            for (int p = 0; p < 4; ++p) {
                const long long rowP = row0 + 4 * p + grp;
                if (rowP < NN) {
                    f32x4 v = __builtin_nontemporal_load(xv + 64 * p + lane);
                    const float t = process_row(v, y[rowP], obs[rowP], sub);
                    if (sub == 0) acc += t;
                }
            }
        }
    }

    // --- block reduction: full-wave shfl, then LDS across waves ---
    #pragma unroll
    for (int off = 1; off < 64; off <<= 1) acc += __shfl_xor(acc, off);

    __shared__ float wsum[8];
    if (lane == 0) wsum[waveInBlock] = acc;
    __syncthreads();
    if (tid == 0) {
        float bsum = 0.f;
        for (int w = 0; w < wavesPerBlock; ++w) bsum += wsum[w];
        atomicAdd(ws_sum, (double)bsum);
    }
}

__global__ void cce_finalize(const double* __restrict__ ws_sum,
                             float* __restrict__ out, int N) {
    if (threadIdx.x == 0 && blockIdx.x == 0) {
        out[0] = (float)(-(*ws_sum) / (double)N);
    }
}

extern "C" void kernel_launch(void* const* d_in, const int* in_sizes, int n_in,
                              void* d_out, int out_size, void* d_ws, size_t ws_size,
                              hipStream_t stream) {
    const float* x   = (const float*)d_in[0];
    const int*   y   = (const int*)d_in[1];
    const float* obs = (const float*)d_in[2];
    int N = in_sizes[1];
    if (N <= 0) N = in_sizes[0] / C;

    double* ws_sum = (double*)d_ws;
    hipMemsetAsync(ws_sum, 0, sizeof(double), stream);

    const int block = 256;
    const long long chunks = ((long long)N + 15) >> 4;          // 16-row wave-tasks
    long long blocksNeeded = (chunks + 3) / 4;                  // 4 waves/block
    int grid = (int)((blocksNeeded < 2048) ? blocksNeeded : 2048);
    if (grid < 1) grid = 1;

    cce_main<<<grid, block, 0, stream>>>(x, y, obs, ws_sum, N);
    cce_finalize<<<1, 64, 0, stream>>>(ws_sum, (float*)d_out, N);
}

// Round 6
// 646.276 us; speedup vs baseline: 1.0434x; 1.0034x over previous
//
#include <hip/hip_runtime.h>

#define EPS_F 1e-12f
constexpr int C = 64;
typedef float f32x4 __attribute__((ext_vector_type(4)));

// --- DPP 16-lane-group allreduce (no LDS pipe, pure VALU) ---------------
// quad_perm xor1 = 0xB1, quad_perm xor2 = 0x4E, row_ror:4 = 0x124,
// row_ror:8 = 0x128. Combine tree is bit-identical (verified absmax==0.0)
// to the original xor-butterfly for the consumed lane.
template <int CTRL>
__device__ __forceinline__ float dpp_movf(float v) {
    return __int_as_float(__builtin_amdgcn_update_dpp(
        0, __float_as_int(v), CTRL, 0xF, 0xF, false));
}
__device__ __forceinline__ float grp_max16(float v) {
    v = fmaxf(v, dpp_movf<0xB1>(v));
    v = fmaxf(v, dpp_movf<0x4E>(v));
    v = fmaxf(v, dpp_movf<0x124>(v));
    v = fmaxf(v, dpp_movf<0x128>(v));
    return v;
}
__device__ __forceinline__ float grp_sum16(float v) {
    v += dpp_movf<0xB1>(v);
    v += dpp_movf<0x4E>(v);
    v += dpp_movf<0x124>(v);
    v += dpp_movf<0x128>(v);
    return v;
}

// One 16-lane subgroup owns one row; sub = lane&15 owns cols 4*sub..4*sub+3.
__device__ __forceinline__ float process_row(f32x4 v, int yy, float ob, int sub) {
    float m = grp_max16(fmaxf(fmaxf(v.x, v.y), fmaxf(v.z, v.w)));

    const float e0 = __expf(v.x - m);
    const float e1 = __expf(v.y - m);
    const float e2 = __expf(v.z - m);
    const float e3 = __expf(v.w - m);
    const float s  = grp_sum16((e0 + e1) + (e2 + e3));

    const float invZ = 1.0f / s;
    const float p0 = fmaxf(e0 * invZ, EPS_F);
    const float p1 = fmaxf(e1 * invZ, EPS_F);
    const float p2 = fmaxf(e2 * invZ, EPS_F);
    const float p3 = fmaxf(e3 * invZ, EPS_F);

    const int col0 = sub << 2;
    const bool use_py = (ob > 0.5f) || (yy == C - 1);

    float part = 0.f;
    if (use_py) {
        if (yy >= col0 && yy < col0 + 4) {
            const int r = yy - col0;
            part = (r == 0) ? p0 : (r == 1) ? p1 : (r == 2) ? p2 : p3;
        }
    } else {
        const int t = yy + 1;
        if (col0 + 0 >= t) part += p0;
        if (col0 + 1 >= t) part += p1;
        if (col0 + 2 >= t) part += p2;
        if (col0 + 3 >= t) part += p3;
    }
    part = grp_sum16(part);
    return __logf(fmaxf(part, EPS_F));
}

// A chunk = 16 consecutive rows (4 KiB of x) + their y/obs.
struct Chunk {
    f32x4 a, b, c, d;
    int   yA, yB, yC, yD;
    float oA, oB, oC, oD;
};

__device__ __forceinline__ Chunk load_chunk(const float* __restrict__ x,
                                            const int* __restrict__ y,
                                            const float* __restrict__ obs,
                                            long long row0, int lane, int grp) {
    Chunk ck;
    const f32x4* xv = reinterpret_cast<const f32x4*>(x + row0 * C);
    ck.a = __builtin_nontemporal_load(xv + lane);
    ck.b = __builtin_nontemporal_load(xv + 64 + lane);
    ck.c = __builtin_nontemporal_load(xv + 128 + lane);
    ck.d = __builtin_nontemporal_load(xv + 192 + lane);
    ck.yA = y[row0 + grp];       ck.oA = obs[row0 + grp];
    ck.yB = y[row0 + 4 + grp];   ck.oB = obs[row0 + 4 + grp];
    ck.yC = y[row0 + 8 + grp];   ck.oC = obs[row0 + 8 + grp];
    ck.yD = y[row0 + 12 + grp];  ck.oD = obs[row0 + 12 + grp];
    return ck;
}

__device__ __forceinline__ float consume_chunk(const Chunk& ck, int sub) {
    return process_row(ck.a, ck.yA, ck.oA, sub)
         + process_row(ck.b, ck.yB, ck.oB, sub)
         + process_row(ck.c, ck.yC, ck.oC, sub)
         + process_row(ck.d, ck.yD, ck.oD, sub);
}

// Software-pipelined grid-stride loop: each main-loop iteration issues the
// loads for TWO chunks (8 KiB / wave in flight) before consuming the first,
// so HBM latency hides under the first chunk's ~500-cycle compute chain.
__global__ __launch_bounds__(256) void cce_main(const float* __restrict__ x,
                                                const int* __restrict__ y,
                                                const float* __restrict__ obs,
                                                double* __restrict__ ws_sum,
                                                int N) {
    const int tid  = threadIdx.x;
    const int lane = tid & 63;
    const int sub  = lane & 15;
    const int grp  = lane >> 4;
    const int waveInBlock   = tid >> 6;
    const int wavesPerBlock = blockDim.x >> 6;

    const long long NN         = N;
    const long long globalWave = (long long)blockIdx.x * wavesPerBlock + waveInBlock;
    const long long numWaves   = (long long)gridDim.x * wavesPerBlock;
    const long long fullChunks = NN >> 4;   // complete 16-row chunks

    float acc = 0.f;

    // --- pipelined pairs ---
    long long chunk = globalWave;
    for (; chunk + numWaves < fullChunks; chunk += 2 * numWaves) {
        const Chunk A = load_chunk(x, y, obs, chunk << 4, lane, grp);
        const Chunk B = load_chunk(x, y, obs, (chunk + numWaves) << 4, lane, grp);
        float t = consume_chunk(A, sub);   // B's loads in flight here
        t += consume_chunk(B, sub);
        if (sub == 0) acc += t;
    }
    // --- leftover single full chunk ---
    if (chunk < fullChunks) {
        const Chunk A = load_chunk(x, y, obs, chunk << 4, lane, grp);
        const float t = consume_chunk(A, sub);
        if (sub == 0) acc += t;
    }
    // --- tail rows (N % 16), handled by wave 0 (empty when N % 16 == 0) ---
    if (globalWave == 0 && (NN & 15)) {
        const long long tailBase = fullChunks << 4;
        const f32x4* xv = reinterpret_cast<const f32x4*>(x + tailBase * C);
        #pragma unroll
        for (int p = 0; p < 4; ++p) {
            const long long rowP = tailBase + 4 * p + grp;
            if (rowP < NN) {
                f32x4 v = xv[64 * p + lane];
                const float t = process_row(v, y[rowP], obs[rowP], sub);
                if (sub == 0) acc += t;
            }
        }
    }

    // --- block reduction: full-wave shfl, then LDS across waves ---
    #pragma unroll
    for (int off = 1; off < 64; off <<= 1) acc += __shfl_xor(acc, off);

    __shared__ float wsum[8];
    if (lane == 0) wsum[waveInBlock] = acc;
    __syncthreads();
    if (tid == 0) {
        float bsum = 0.f;
        for (int w = 0; w < wavesPerBlock; ++w) bsum += wsum[w];
        atomicAdd(ws_sum, (double)bsum);
    }
}

__global__ void cce_finalize(const double* __restrict__ ws_sum,
                             float* __restrict__ out, int N) {
    if (threadIdx.x == 0 && blockIdx.x == 0) {
        out[0] = (float)(-(*ws_sum) / (double)N);
    }
}

extern "C" void kernel_launch(void* const* d_in, const int* in_sizes, int n_in,
                              void* d_out, int out_size, void* d_ws, size_t ws_size,
                              hipStream_t stream) {
    const float* x   = (const float*)d_in[0];
    const int*   y   = (const int*)d_in[1];
    const float* obs = (const float*)d_in[2];
    int N = in_sizes[1];
    if (N <= 0) N = in_sizes[0] / C;

    double* ws_sum = (double*)d_ws;
    hipMemsetAsync(ws_sum, 0, sizeof(double), stream);

    const int block = 256;
    const long long chunks = ((long long)N + 15) >> 4;          // 16-row wave-tasks
    long long blocksNeeded = (chunks + 3) / 4;                  // 4 waves/block
    int grid = (int)((blocksNeeded < 2048) ? blocksNeeded : 2048);
    if (grid < 1) grid = 1;

    cce_main<<<grid, block, 0, stream>>>(x, y, obs, ws_sum, N);
    cce_finalize<<<1, 64, 0, stream>>>(ws_sum, (float*)d_out, N);
}